// Round 6
// baseline (27141.345 us; speedup 1.0000x reference)
//
#include <hip/hip_runtime.h>

// ---------------------------------------------------------------------------
// CNF forward: 2 blocks x Tsit5(10 steps x 6 stages).
// Round 6:
//  - jac v3: 32x32x16 MFMA (2x FLOP/LDS-byte), 1 sample/block, 4 waves,
//    wave tile 128x128 (acc 256 VGPR + packed-bf16 J 128 VGPR), conflict-free
//    [kslot][row] LDS layout, BK=32 double-buffered.
//  - fwd L0 fused with prep_split (in-register yi build + split + ds_write).
// ---------------------------------------------------------------------------

using short8 = __attribute__((ext_vector_type(8))) short;
using u16x8  = __attribute__((ext_vector_type(8))) unsigned short;
using f32x4v = __attribute__((ext_vector_type(4))) float;
using f32x16 = __attribute__((ext_vector_type(16))) float;

__device__ __forceinline__ unsigned short f2bf(float f) {
  union { float f; unsigned u; } v; v.f = f;
  unsigned r = v.u + 0x7fffu + ((v.u >> 16) & 1u);
  return (unsigned short)(r >> 16);
}
__device__ __forceinline__ float bf2f(unsigned short h) {
  union { unsigned u; float f; } v; v.u = ((unsigned)h) << 16; return v.f;
}

typedef const __attribute__((address_space(1))) void gas_t;
typedef __attribute__((address_space(3))) void las_t;
__device__ __forceinline__ void gl_lds16(const void* g, void* l) {
  __builtin_amdgcn_global_load_lds((gas_t*)g, (las_t*)l, 16, 0, 0);
}

struct Coef5 { float v[5]; };
struct Coef6 { float v[6]; };

// ---------------------------------------------------------------------------
__global__ __launch_bounds__(256) void init_state(const float* __restrict__ y_in,
                                                  float* __restrict__ y,
                                                  float* __restrict__ lp) {
  int i = blockIdx.x * 256 + threadIdx.x;
  if (i < 512 * 128) y[i] = y_in[i];
  if (i < 512) lp[i] = 0.f;
}

// Weight prep (per ODE block):
//  w0y[j][a] = bf16(W0[1+j][a])   128x512   (jac GEMM-J B)
//  w0t[n][k] = split(W0[1+k][n])  512x128   (fwd L0 B)
//  w1t[b][a] = split(W1[a][b])    512x512   (fwd L1 B; hi = jac GEMM-J A)
//  w2t[c][b] = split(W2[b][c])    512x512   (fwd L2 B)
//  w3t[j][c] = split(W3[c][j])    128x512   (fwd L3 B; hi = jac GEMM-G B)
//  w2n[b][c] = bf16(W2[b][c])     512x512   (jac GEMM-G A)
__global__ __launch_bounds__(256) void cast_weights(
    const float* __restrict__ W0, const float* __restrict__ W1,
    const float* __restrict__ W2, const float* __restrict__ W3,
    unsigned short* __restrict__ w0y,
    unsigned short* __restrict__ w0tH, unsigned short* __restrict__ w0tL,
    unsigned short* __restrict__ w1tH, unsigned short* __restrict__ w1tL,
    unsigned short* __restrict__ w2tH, unsigned short* __restrict__ w2tL,
    unsigned short* __restrict__ w3tH, unsigned short* __restrict__ w3tL,
    unsigned short* __restrict__ w2n) {
  int i = blockIdx.x * 256 + threadIdx.x;
  if (i < 65536) {
    int j = i >> 9, a = i & 511;
    w0y[i] = f2bf(W0[(1 + j) * 512 + a]);
    return;
  }
  i -= 65536;
  if (i >= 2 * 65536 + 2 * 262144) {
    int q = i - (2 * 65536 + 2 * 262144);
    if (q < 262144) w2n[q] = f2bf(W2[q]);
    return;
  }
  float v;
  unsigned short* dh;
  unsigned short* dl;
  int di;
  if (i < 65536) {
    int n = i >> 7, k = i & 127;
    v = W0[(1 + k) * 512 + n]; dh = w0tH; dl = w0tL; di = i;
  } else if (i < 65536 + 262144) {
    int q = i - 65536; int n = q >> 9, k = q & 511;
    v = W1[k * 512 + n]; dh = w1tH; dl = w1tL; di = q;
  } else if (i < 65536 + 2 * 262144) {
    int q = i - 65536 - 262144; int c = q >> 9, b = q & 511;
    v = W2[b * 512 + c]; dh = w2tH; dl = w2tL; di = q;
  } else {
    int q = i - 65536 - 2 * 262144; int j = q >> 9, c = q & 511;
    v = W3[c * 128 + j]; dh = w3tH; dl = w3tL; di = q;
  }
  unsigned short hi = f2bf(v);
  dh[di] = hi;
  dl[di] = f2bf(v - bf2f(hi));
}

// ---------------------------------------------------------------------------
// fwd L0 fused with stage prep: A = split(y + sum ca*ky) built in-register,
// B = w0t staged. Tile 32x32, K=128 single shot. relu -> h0 hi/lo.
// ---------------------------------------------------------------------------
__global__ __launch_bounds__(256, 2) void fwd_l0(
    const float* __restrict__ yb, const float* __restrict__ kyb, Coef5 ca, int nc,
    const unsigned short* __restrict__ WtH, const unsigned short* __restrict__ WtL,
    const float* __restrict__ bias, const float* __restrict__ wrow0, float tval,
    unsigned short* __restrict__ Hhi, unsigned short* __restrict__ Hlo) {
  __shared__ unsigned short AsH[4096], AsL[4096], BsH[4096], BsL[4096];
  const int t = threadIdx.x, l = t & 63;
  const int wv = t >> 6, wm = wv >> 1, wn = wv & 1;
  const int lr = l & 15, lg = l >> 4, lr7 = lr & 7;
  const int m0 = blockIdx.y * 32, n0 = blockIdx.x * 32;

#pragma unroll
  for (int r = 0; r < 2; ++r) {
    int g = r * 256 + t;
    int row = g >> 4;
    int gc = (g & 15) ^ (row & 7);
    size_t bo = (size_t)(n0 + row) * 128 + gc * 8;
    int db = (r * 256 + (t & 192)) * 16;
    gl_lds16(WtH + bo, (char*)BsH + db);
    gl_lds16(WtL + bo, (char*)BsL + db);
  }
  {
    int row = t >> 3, seg = t & 7;
    int gidx = (m0 + row) * 128 + seg * 16;
    float x[16];
#pragma unroll
    for (int q = 0; q < 4; ++q) *(float4*)&x[q * 4] = *(const float4*)&yb[gidx + q * 4];
    for (int j2 = 0; j2 < nc; ++j2) {
      float c = ca.v[j2];
#pragma unroll
      for (int q = 0; q < 4; ++q) {
        float4 u = *(const float4*)&kyb[j2 * 65536 + gidx + q * 4];
        x[q * 4 + 0] = fmaf(c, u.x, x[q * 4 + 0]);
        x[q * 4 + 1] = fmaf(c, u.y, x[q * 4 + 1]);
        x[q * 4 + 2] = fmaf(c, u.z, x[q * 4 + 2]);
        x[q * 4 + 3] = fmaf(c, u.w, x[q * 4 + 3]);
      }
    }
    u16x8 h8[2], l8[2];
#pragma unroll
    for (int e = 0; e < 16; ++e) {
      unsigned short hh = f2bf(x[e]);
      h8[e >> 3][e & 7] = hh;
      l8[e >> 3][e & 7] = f2bf(x[e] - bf2f(hh));
    }
#pragma unroll
    for (int h = 0; h < 2; ++h) {
      int gx = (seg * 2 + h) ^ (row & 7);
      *(u16x8*)((char*)AsH + row * 256 + gx * 16) = h8[h];
      *(u16x8*)((char*)AsL + row * 256 + gx * 16) = l8[h];
    }
  }
  __syncthreads();

  f32x4v acc = {0.f, 0.f, 0.f, 0.f};
#pragma unroll
  for (int ks = 0; ks < 4; ++ks) {
    int sl = ((ks * 4 + lg) ^ lr7) << 4;
    int ab = (wm * 16 + lr) * 256 + sl;
    int bb = (wn * 16 + lr) * 256 + sl;
    short8 ah = *(const short8*)((const char*)AsH + ab);
    short8 al = *(const short8*)((const char*)AsL + ab);
    short8 bh = *(const short8*)((const char*)BsH + bb);
    short8 bl = *(const short8*)((const char*)BsL + bb);
    acc = __builtin_amdgcn_mfma_f32_16x16x32_bf16(ah, bh, acc, 0, 0, 0);
    acc = __builtin_amdgcn_mfma_f32_16x16x32_bf16(ah, bl, acc, 0, 0, 0);
    acc = __builtin_amdgcn_mfma_f32_16x16x32_bf16(al, bh, acc, 0, 0, 0);
  }

  int n = n0 + wn * 16 + lr;
  float be = fmaf(tval, wrow0[n], bias[n]);
#pragma unroll
  for (int r = 0; r < 4; ++r) {
    int m = m0 + wm * 16 + lg * 4 + r;
    float v = fmaxf(acc[r] + be, 0.f);
    unsigned short h = f2bf(v);
    Hhi[m * 512 + n] = h;
    Hlo[m * 512 + n] = f2bf(v - bf2f(h));
  }
}

// ---------------------------------------------------------------------------
// fwd split-bf16 MFMA GEMM (L1/L2/L3): C = act(A @ W + bias).
// Tile 32x32, BK=128, 4 waves 2x2, wave 16x16, 2-phase pipelined staging.
// ---------------------------------------------------------------------------
template <bool RELU>
__global__ __launch_bounds__(256, 2) void fwd_mfma(
    const unsigned short* __restrict__ Ahi, const unsigned short* __restrict__ Alo,
    const unsigned short* __restrict__ WtH, const unsigned short* __restrict__ WtL,
    const float* __restrict__ bias,
    float* __restrict__ Cf, unsigned short* __restrict__ Hhi,
    unsigned short* __restrict__ Hlo, int N, int K) {
  __shared__ unsigned short AsH[2][4096], AsL[2][4096], BsH[2][4096], BsL[2][4096];
  const int t = threadIdx.x, l = t & 63, w = t >> 6;
  const int wm = w >> 1, wn = w & 1, lr = l & 15, lg = l >> 4;
  const int m0 = blockIdx.y * 32, n0 = blockIdx.x * 32;
  const int lr7 = lr & 7;

  auto stage = [&](int cur, int k0) {
#pragma unroll
    for (int r = 0; r < 2; ++r) {
      int g = r * 256 + t;
      int row = g >> 4, gc = g & 15;
      size_t co = (size_t)k0 + ((gc ^ (row & 7)) << 3);
      size_t ao = (size_t)(m0 + row) * K + co;
      size_t bo = (size_t)(n0 + row) * K + co;
      int db = (r * 256 + (t & 192)) * 16;
      gl_lds16(Ahi + ao, (char*)AsH[cur] + db);
      gl_lds16(Alo + ao, (char*)AsL[cur] + db);
      gl_lds16(WtH + bo, (char*)BsH[cur] + db);
      gl_lds16(WtL + bo, (char*)BsL[cur] + db);
    }
  };

  f32x4v acc = {0.f, 0.f, 0.f, 0.f};
  stage(0, 0);
  __syncthreads();
  int cur = 0;
  for (int k0 = 0; k0 < K; k0 += 128) {
    if (k0 + 128 < K) stage(cur ^ 1, k0 + 128);
#pragma unroll
    for (int ks = 0; ks < 4; ++ks) {
      int sl = ((ks * 4 + lg) ^ lr7) << 4;
      int ab = (wm * 16 + lr) * 256 + sl;
      int bb = (wn * 16 + lr) * 256 + sl;
      short8 ah = *(const short8*)((const char*)AsH[cur] + ab);
      short8 al = *(const short8*)((const char*)AsL[cur] + ab);
      short8 bh = *(const short8*)((const char*)BsH[cur] + bb);
      short8 bl = *(const short8*)((const char*)BsL[cur] + bb);
      acc = __builtin_amdgcn_mfma_f32_16x16x32_bf16(ah, bh, acc, 0, 0, 0);
      acc = __builtin_amdgcn_mfma_f32_16x16x32_bf16(ah, bl, acc, 0, 0, 0);
      acc = __builtin_amdgcn_mfma_f32_16x16x32_bf16(al, bh, acc, 0, 0, 0);
    }
    __syncthreads();
    cur ^= 1;
  }

  int n = n0 + wn * 16 + lr;
  float be = bias[n];
#pragma unroll
  for (int r = 0; r < 4; ++r) {
    int m = m0 + wm * 16 + lg * 4 + r;
    float v = acc[r] + be;
    if (RELU) {
      v = fmaxf(v, 0.f);
      unsigned short h = f2bf(v);
      Hhi[m * N + n] = h;
      Hlo[m * N + n] = f2bf(v - bf2f(h));
    } else {
      Cf[m * N + n] = v;
    }
  }
}

// ---------------------------------------------------------------------------
// Fused Jacobian-trace kernel v3. One sample per block, 4 waves (M-split),
// wave tile 128b x 128j, 32x32x16 MFMA, K=512, BK=32 double-buffered.
//   J1[b][j] = sum_a w1t[b][a]*(D0[a]*w0y[j][a])
//   G [b][j] = sum_c w2n[b][c]*(D2[c]*w3t[j][c])
//   klp[s]   = sum_{b,j} D1[b]*J1[b][j]*G[b][j]
// LDS [kslot][row] layout: fragment reads are contiguous 16B runs over
// consecutive rows -> bank-conflict-free, no swizzle needed.
// ---------------------------------------------------------------------------
__global__ __launch_bounds__(256, 1) void jac_fused(
    const unsigned short* __restrict__ w1t, const unsigned short* __restrict__ w0y,
    const unsigned short* __restrict__ w2n, const unsigned short* __restrict__ w3t,
    const unsigned short* __restrict__ d0m, const unsigned short* __restrict__ d1m,
    const unsigned short* __restrict__ d2m, float* __restrict__ klp) {
  __shared__ unsigned short As[2][16384];  // [kslot4][512row][8] = 32KB x2
  __shared__ unsigned short Bs[2][4096];   // [kslot4][128row][8] =  8KB x2
  __shared__ unsigned short Ms[3][512];
  __shared__ float red[4];
  const int s = blockIdx.x;
  const int t = threadIdx.x, l = t & 63, w = t >> 6;
  const int lr = l & 31, hi = l >> 5;

  if (w == 0) gl_lds16(d0m + (size_t)s * 512 + l * 8, (void*)Ms[0]);
  else if (w == 1) gl_lds16(d1m + (size_t)s * 512 + l * 8, (void*)Ms[1]);
  else if (w == 2) gl_lds16(d2m + (size_t)s * 512 + l * 8, (void*)Ms[2]);
  __syncthreads();
  {
    unsigned* M = (unsigned*)&Ms[0][0];
#pragma unroll
    for (int q = 0; q < 3; ++q) {
      unsigned v = M[q * 256 + t];
      M[q * 256 + t] = ((v & 0xFFFFu) ? 0xFFFFu : 0u) | ((v >> 16) ? 0xFFFF0000u : 0u);
    }
  }
  __syncthreads();

  auto stageA = [&](int buf, const unsigned short* Ab, int k0) {
#pragma unroll
    for (int i = 0; i < 8; ++i) {
      int u = i * 4 + w;
      int ks = u & 3, sp = u >> 2;
      gl_lds16(Ab + (size_t)(sp * 64 + l) * 512 + k0 + ks * 8,
               (char*)As[buf] + ks * 8192 + sp * 1024);
    }
  };
  auto stageB = [&](int buf, const unsigned short* Bb, int k0) {
#pragma unroll
    for (int i = 0; i < 2; ++i) {
      int u = i * 4 + w;
      int ks = u & 3, sp = u >> 2;
      gl_lds16(Bb + (size_t)(sp * 64 + l) * 512 + k0 + ks * 8,
               (char*)Bs[buf] + ks * 2048 + sp * 1024);
    }
  };

  auto phase = [&](f32x16 (&acc)[4][4], const unsigned short* Ab,
                   const unsigned short* Bb, const unsigned short* Mk) {
    stageA(0, Ab, 0);
    stageB(0, Bb, 0);
    __syncthreads();
    int cur = 0;
    for (int k0 = 0; k0 < 512; k0 += 32) {
      if (k0 + 32 < 512) {
        stageA(cur ^ 1, Ab, k0 + 32);
        stageB(cur ^ 1, Bb, k0 + 32);
      }
#pragma unroll
      for (int kst = 0; kst < 2; ++kst) {
        const int ks = kst * 2 + hi;
        short8 af[4];
#pragma unroll
        for (int mt = 0; mt < 4; ++mt)
          af[mt] = *(const short8*)((const char*)As[cur] + ks * 8192 +
                                    (w * 128 + mt * 32 + lr) * 16);
        u16x8 mk = *(const u16x8*)&Mk[k0 + ks * 8];
#pragma unroll
        for (int nt = 0; nt < 4; ++nt) {
          u16x8 bv = *(const u16x8*)((const char*)Bs[cur] + ks * 2048 +
                                     (nt * 32 + lr) * 16);
          short8 bm = (short8)(bv & mk);
#pragma unroll
          for (int mt = 0; mt < 4; ++mt)
            acc[mt][nt] = __builtin_amdgcn_mfma_f32_32x32x16_bf16(
                af[mt], bm, acc[mt][nt], 0, 0, 0);
        }
      }
      __syncthreads();
      cur ^= 1;
    }
  };

  f32x16 acc[4][4];
#pragma unroll
  for (int mt = 0; mt < 4; ++mt)
#pragma unroll
    for (int nt = 0; nt < 4; ++nt) acc[mt][nt] = (f32x16)(0.f);

  phase(acc, w1t, w0y, Ms[0]);

  // pack J -> bf16 pairs (128 VGPR), then reuse acc for G
  unsigned pj[4][4][8];
#pragma unroll
  for (int mt = 0; mt < 4; ++mt)
#pragma unroll
    for (int nt = 0; nt < 4; ++nt)
#pragma unroll
      for (int p = 0; p < 8; ++p)
        asm("v_cvt_pk_bf16_f32 %0, %1, %2"
            : "=v"(pj[mt][nt][p])
            : "v"(acc[mt][nt][2 * p]), "v"(acc[mt][nt][2 * p + 1]));

#pragma unroll
  for (int mt = 0; mt < 4; ++mt)
#pragma unroll
    for (int nt = 0; nt < 4; ++nt) acc[mt][nt] = (f32x16)(0.f);

  phase(acc, w2n, w3t, Ms[2]);

  // dot: part = sum D1[b] * J * G   (C/D layout: row=(r&3)+8*(r>>2)+4*hi)
  float part = 0.f;
#pragma unroll
  for (int mt = 0; mt < 4; ++mt)
#pragma unroll
    for (int q = 0; q < 4; ++q) {
      ushort4 m4 = *(const ushort4*)&Ms[1][w * 128 + mt * 32 + q * 8 + 4 * hi];
      const unsigned short mm[4] = {m4.x, m4.y, m4.z, m4.w};
#pragma unroll
      for (int e = 0; e < 4; ++e) {
        const int r = q * 4 + e;
        float fl = mm[e] ? 1.f : 0.f;
#pragma unroll
        for (int nt = 0; nt < 4; ++nt) {
          unsigned pw = pj[mt][nt][r >> 1];
          unsigned short jb = (r & 1) ? (unsigned short)(pw >> 16)
                                      : (unsigned short)(pw & 0xFFFFu);
          part = fmaf(fl * bf2f(jb), acc[mt][nt][r], part);
        }
      }
    }

#pragma unroll
  for (int off = 1; off < 64; off <<= 1) part += __shfl_xor(part, off);
  if (l == 0) red[w] = part;
  __syncthreads();
  if (t == 0) klp[s] = red[0] + red[1] + red[2] + red[3];
}

// y += sum_i db[i]*ky[i];  lp += sum_i db[i]*klp[i][s]
__global__ __launch_bounds__(256) void step_update(float* __restrict__ y,
                                                   float* __restrict__ lp,
                                                   const float* __restrict__ ky,
                                                   const float* __restrict__ klp_part,
                                                   Coef6 db) {
  int i = blockIdx.x * 256 + threadIdx.x;
  if (i < 65536) {
    float a = y[i];
#pragma unroll
    for (int j = 0; j < 6; ++j) a += db.v[j] * ky[j * 65536 + i];
    y[i] = a;
  }
  if (i < 512) {
    float l = lp[i];
#pragma unroll
    for (int j = 0; j < 6; ++j) l += db.v[j] * klp_part[j * 512 + i];
    lp[i] = l;
  }
}

__global__ __launch_bounds__(64) void finalize(const float* __restrict__ y,
                                               const float* __restrict__ lp,
                                               float* __restrict__ out) {
  int s = blockIdx.x, l = threadIdx.x;
  float v0 = y[s * 128 + l], v1 = y[s * 128 + 64 + l];
  float sum = v0 * v0 + v1 * v1;
#pragma unroll
  for (int off = 32; off; off >>= 1) sum += __shfl_down(sum, off);
  if (l == 0) out[s] = lp[s] + (-0.5f) * (1.8378770664093453f + sum);
}

// ---------------------------------------------------------------------------
extern "C" void kernel_launch(void* const* d_in, const int* in_sizes, int n_in,
                              void* d_out, int out_size, void* d_ws, size_t ws_size,
                              hipStream_t stream) {
  const float* y_in = (const float*)d_in[0];
  const float* Ws0 = (const float*)d_in[1];
  const float* bs0 = (const float*)d_in[2];
  const float* Ws1 = (const float*)d_in[3];
  const float* bs1 = (const float*)d_in[4];
  const float* Ws2 = (const float*)d_in[5];
  const float* bs2 = (const float*)d_in[6];
  const float* Ws3 = (const float*)d_in[7];
  const float* bs3 = (const float*)d_in[8];
  float* out = (float*)d_out;

  char* ws = (char*)d_ws;
  size_t off = 0;
  auto alloc = [&](size_t bytes) {
    void* p = ws + off;
    off = (off + bytes + 255) & ~(size_t)255;
    return p;
  };
  float* y  = (float*)alloc(65536 * 4);
  float* lp = (float*)alloc(512 * 4);
  unsigned short* h0hi = (unsigned short*)alloc(262144 * 2);
  unsigned short* h0lo = (unsigned short*)alloc(262144 * 2);
  unsigned short* h1hi = (unsigned short*)alloc(262144 * 2);
  unsigned short* h1lo = (unsigned short*)alloc(262144 * 2);
  unsigned short* h2hi = (unsigned short*)alloc(262144 * 2);
  unsigned short* h2lo = (unsigned short*)alloc(262144 * 2);
  float* ky  = (float*)alloc(6 * 65536 * 4);
  float* klp = (float*)alloc(6 * 512 * 4);
  unsigned short* w0y  = (unsigned short*)alloc(65536 * 2);
  unsigned short* w0tH = (unsigned short*)alloc(65536 * 2);
  unsigned short* w0tL = (unsigned short*)alloc(65536 * 2);
  unsigned short* w1tH = (unsigned short*)alloc(262144 * 2);
  unsigned short* w1tL = (unsigned short*)alloc(262144 * 2);
  unsigned short* w2tH = (unsigned short*)alloc(262144 * 2);
  unsigned short* w2tL = (unsigned short*)alloc(262144 * 2);
  unsigned short* w3tH = (unsigned short*)alloc(65536 * 2);
  unsigned short* w3tL = (unsigned short*)alloc(65536 * 2);
  unsigned short* w2n  = (unsigned short*)alloc(262144 * 2);
  (void)ws_size; (void)in_sizes; (void)n_in; (void)out_size;

  static const double DT = -0.1;
  static const double TC[6] = {0.0, 0.161, 0.327, 0.9, 0.9800255409045097, 1.0};
  static const double TA[6][5] = {
      {0, 0, 0, 0, 0},
      {0.161, 0, 0, 0, 0},
      {-0.008480655492356989, 0.335480655492357, 0, 0, 0},
      {2.8971530571054935, -6.359448489975075, 4.3622954328695815, 0, 0},
      {5.325864828439257, -11.748883564062828, 7.4955393428898365, -0.09249506636175525, 0},
      {5.86145544294642, -12.92096931784711, 8.159367898576159, -0.071584973281401,
       -0.028269050394068383}};
  static const double TB[6] = {0.09646076681806523, 0.01, 0.4798896504144996,
                               1.379008574103742, -3.290069515436081, 2.324710524099774};

  init_state<<<dim3(256), dim3(256), 0, stream>>>(y_in, y, lp);

  for (int blk = 0; blk < 2; ++blk) {
    const float* W0 = Ws0 + blk * 129 * 512;
    const float* b0 = bs0 + blk * 512;
    const float* W1 = Ws1 + blk * 262144;
    const float* b1 = bs1 + blk * 512;
    const float* W2 = Ws2 + blk * 262144;
    const float* b2 = bs2 + blk * 512;
    const float* W3 = Ws3 + blk * 65536;
    const float* b3 = bs3 + blk * 128;

    cast_weights<<<dim3(3840), dim3(256), 0, stream>>>(
        W0, W1, W2, W3, w0y, w0tH, w0tL, w1tH, w1tL, w2tH, w2tL, w3tH, w3tL, w2n);

    for (int n = 0; n < 10; ++n) {
      float t = 1.0f + (-0.1f) * (float)n;
      for (int i = 0; i < 6; ++i) {
        float ti = t + (float)(TC[i] * DT);
        Coef5 ca;
        for (int j = 0; j < 5; ++j) ca.v[j] = (j < i) ? (float)(DT * TA[i][j]) : 0.f;

        fwd_l0<<<dim3(16, 16), 256, 0, stream>>>(
            y, ky, ca, i, w0tH, w0tL, b0, W0, ti, h0hi, h0lo);
        fwd_mfma<true><<<dim3(16, 16), 256, 0, stream>>>(
            h0hi, h0lo, w1tH, w1tL, b1, nullptr, h1hi, h1lo, 512, 512);
        fwd_mfma<true><<<dim3(16, 16), 256, 0, stream>>>(
            h1hi, h1lo, w2tH, w2tL, b2, nullptr, h2hi, h2lo, 512, 512);
        fwd_mfma<false><<<dim3(4, 16), 256, 0, stream>>>(
            h2hi, h2lo, w3tH, w3tL, b3, ky + i * 65536, nullptr, nullptr, 128, 512);
        jac_fused<<<dim3(512), 256, 0, stream>>>(
            w1tH, w0y, w2n, w3tH, h0hi, h1hi, h2hi, klp + i * 512);
      }
      Coef6 db;
      for (int i2 = 0; i2 < 6; ++i2) db.v[i2] = (float)(DT * TB[i2]);
      step_update<<<dim3(256), dim3(256), 0, stream>>>(y, lp, ky, klp, db);
    }
  }
  finalize<<<dim3(512), dim3(64), 0, stream>>>(y, lp, out);
}

// Round 7
// 12302.247 us; speedup vs baseline: 2.2062x; 2.2062x over previous
//
#include <hip/hip_runtime.h>

// ---------------------------------------------------------------------------
// CNF forward: 2 blocks x Tsit5(10 steps x 6 stages).
// Round 7:
//  - jac v4: R4 fragment geometry + 2 samples/block (51 FLOP/LDS-byte),
//    G-phase first then packed to bf16 (64 VGPR), J-phase reuses acc, dot
//    epilogue; [ks][row] conflict-free LDS; T3-lite 2-phase pipeline;
//    launch_bounds(256,2) caps VGPR at 256 (R6's spill was the regression).
//  - fwd kernels unchanged from R6 (32x32 tiles, fused L0).
// ---------------------------------------------------------------------------

using short8 = __attribute__((ext_vector_type(8))) short;
using u16x8  = __attribute__((ext_vector_type(8))) unsigned short;
using f32x4v = __attribute__((ext_vector_type(4))) float;

__device__ __forceinline__ unsigned short f2bf(float f) {
  union { float f; unsigned u; } v; v.f = f;
  unsigned r = v.u + 0x7fffu + ((v.u >> 16) & 1u);
  return (unsigned short)(r >> 16);
}
__device__ __forceinline__ float bf2f(unsigned short h) {
  union { unsigned u; float f; } v; v.u = ((unsigned)h) << 16; return v.f;
}

typedef const __attribute__((address_space(1))) void gas_t;
typedef __attribute__((address_space(3))) void las_t;
__device__ __forceinline__ void gl_lds16(const void* g, void* l) {
  __builtin_amdgcn_global_load_lds((gas_t*)g, (las_t*)l, 16, 0, 0);
}

struct Coef5 { float v[5]; };
struct Coef6 { float v[6]; };

// ---------------------------------------------------------------------------
__global__ __launch_bounds__(256) void init_state(const float* __restrict__ y_in,
                                                  float* __restrict__ y,
                                                  float* __restrict__ lp) {
  int i = blockIdx.x * 256 + threadIdx.x;
  if (i < 512 * 128) y[i] = y_in[i];
  if (i < 512) lp[i] = 0.f;
}

// Weight prep (per ODE block):
//  w0y[j][a] = bf16(W0[1+j][a])   128x512   (jac GEMM-J B)
//  w0t[n][k] = split(W0[1+k][n])  512x128   (fwd L0 B)
//  w1t[b][a] = split(W1[a][b])    512x512   (fwd L1 B; hi = jac GEMM-J A)
//  w2t[c][b] = split(W2[b][c])    512x512   (fwd L2 B)
//  w3t[j][c] = split(W3[c][j])    128x512   (fwd L3 B; hi = jac GEMM-G B)
//  w2n[b][c] = bf16(W2[b][c])     512x512   (jac GEMM-G A)
__global__ __launch_bounds__(256) void cast_weights(
    const float* __restrict__ W0, const float* __restrict__ W1,
    const float* __restrict__ W2, const float* __restrict__ W3,
    unsigned short* __restrict__ w0y,
    unsigned short* __restrict__ w0tH, unsigned short* __restrict__ w0tL,
    unsigned short* __restrict__ w1tH, unsigned short* __restrict__ w1tL,
    unsigned short* __restrict__ w2tH, unsigned short* __restrict__ w2tL,
    unsigned short* __restrict__ w3tH, unsigned short* __restrict__ w3tL,
    unsigned short* __restrict__ w2n) {
  int i = blockIdx.x * 256 + threadIdx.x;
  if (i < 65536) {
    int j = i >> 9, a = i & 511;
    w0y[i] = f2bf(W0[(1 + j) * 512 + a]);
    return;
  }
  i -= 65536;
  if (i >= 2 * 65536 + 2 * 262144) {
    int q = i - (2 * 65536 + 2 * 262144);
    if (q < 262144) w2n[q] = f2bf(W2[q]);
    return;
  }
  float v;
  unsigned short* dh;
  unsigned short* dl;
  int di;
  if (i < 65536) {
    int n = i >> 7, k = i & 127;
    v = W0[(1 + k) * 512 + n]; dh = w0tH; dl = w0tL; di = i;
  } else if (i < 65536 + 262144) {
    int q = i - 65536; int n = q >> 9, k = q & 511;
    v = W1[k * 512 + n]; dh = w1tH; dl = w1tL; di = q;
  } else if (i < 65536 + 2 * 262144) {
    int q = i - 65536 - 262144; int c = q >> 9, b = q & 511;
    v = W2[b * 512 + c]; dh = w2tH; dl = w2tL; di = q;
  } else {
    int q = i - 65536 - 2 * 262144; int j = q >> 9, c = q & 511;
    v = W3[c * 128 + j]; dh = w3tH; dl = w3tL; di = q;
  }
  unsigned short hi = f2bf(v);
  dh[di] = hi;
  dl[di] = f2bf(v - bf2f(hi));
}

// ---------------------------------------------------------------------------
// fwd L0 fused with stage prep: A = split(y + sum ca*ky) built in-register,
// B = w0t staged. Tile 32x32, K=128 single shot. relu -> h0 hi/lo.
// ---------------------------------------------------------------------------
__global__ __launch_bounds__(256, 2) void fwd_l0(
    const float* __restrict__ yb, const float* __restrict__ kyb, Coef5 ca, int nc,
    const unsigned short* __restrict__ WtH, const unsigned short* __restrict__ WtL,
    const float* __restrict__ bias, const float* __restrict__ wrow0, float tval,
    unsigned short* __restrict__ Hhi, unsigned short* __restrict__ Hlo) {
  __shared__ unsigned short AsH[4096], AsL[4096], BsH[4096], BsL[4096];
  const int t = threadIdx.x, l = t & 63;
  const int wv = t >> 6, wm = wv >> 1, wn = wv & 1;
  const int lr = l & 15, lg = l >> 4, lr7 = lr & 7;
  const int m0 = blockIdx.y * 32, n0 = blockIdx.x * 32;

#pragma unroll
  for (int r = 0; r < 2; ++r) {
    int g = r * 256 + t;
    int row = g >> 4;
    int gc = (g & 15) ^ (row & 7);
    size_t bo = (size_t)(n0 + row) * 128 + gc * 8;
    int db = (r * 256 + (t & 192)) * 16;
    gl_lds16(WtH + bo, (char*)BsH + db);
    gl_lds16(WtL + bo, (char*)BsL + db);
  }
  {
    int row = t >> 3, seg = t & 7;
    int gidx = (m0 + row) * 128 + seg * 16;
    float x[16];
#pragma unroll
    for (int q = 0; q < 4; ++q) *(float4*)&x[q * 4] = *(const float4*)&yb[gidx + q * 4];
    for (int j2 = 0; j2 < nc; ++j2) {
      float c = ca.v[j2];
#pragma unroll
      for (int q = 0; q < 4; ++q) {
        float4 u = *(const float4*)&kyb[j2 * 65536 + gidx + q * 4];
        x[q * 4 + 0] = fmaf(c, u.x, x[q * 4 + 0]);
        x[q * 4 + 1] = fmaf(c, u.y, x[q * 4 + 1]);
        x[q * 4 + 2] = fmaf(c, u.z, x[q * 4 + 2]);
        x[q * 4 + 3] = fmaf(c, u.w, x[q * 4 + 3]);
      }
    }
    u16x8 h8[2], l8[2];
#pragma unroll
    for (int e = 0; e < 16; ++e) {
      unsigned short hh = f2bf(x[e]);
      h8[e >> 3][e & 7] = hh;
      l8[e >> 3][e & 7] = f2bf(x[e] - bf2f(hh));
    }
#pragma unroll
    for (int h = 0; h < 2; ++h) {
      int gx = (seg * 2 + h) ^ (row & 7);
      *(u16x8*)((char*)AsH + row * 256 + gx * 16) = h8[h];
      *(u16x8*)((char*)AsL + row * 256 + gx * 16) = l8[h];
    }
  }
  __syncthreads();

  f32x4v acc = {0.f, 0.f, 0.f, 0.f};
#pragma unroll
  for (int ks = 0; ks < 4; ++ks) {
    int sl = ((ks * 4 + lg) ^ lr7) << 4;
    int ab = (wm * 16 + lr) * 256 + sl;
    int bb = (wn * 16 + lr) * 256 + sl;
    short8 ah = *(const short8*)((const char*)AsH + ab);
    short8 al = *(const short8*)((const char*)AsL + ab);
    short8 bh = *(const short8*)((const char*)BsH + bb);
    short8 bl = *(const short8*)((const char*)BsL + bb);
    acc = __builtin_amdgcn_mfma_f32_16x16x32_bf16(ah, bh, acc, 0, 0, 0);
    acc = __builtin_amdgcn_mfma_f32_16x16x32_bf16(ah, bl, acc, 0, 0, 0);
    acc = __builtin_amdgcn_mfma_f32_16x16x32_bf16(al, bh, acc, 0, 0, 0);
  }

  int n = n0 + wn * 16 + lr;
  float be = fmaf(tval, wrow0[n], bias[n]);
#pragma unroll
  for (int r = 0; r < 4; ++r) {
    int m = m0 + wm * 16 + lg * 4 + r;
    float v = fmaxf(acc[r] + be, 0.f);
    unsigned short h = f2bf(v);
    Hhi[m * 512 + n] = h;
    Hlo[m * 512 + n] = f2bf(v - bf2f(h));
  }
}

// ---------------------------------------------------------------------------
// fwd split-bf16 MFMA GEMM (L1/L2/L3): C = act(A @ W + bias).
// Tile 32x32, BK=128, 4 waves 2x2, wave 16x16, 2-phase pipelined staging.
// ---------------------------------------------------------------------------
template <bool RELU>
__global__ __launch_bounds__(256, 2) void fwd_mfma(
    const unsigned short* __restrict__ Ahi, const unsigned short* __restrict__ Alo,
    const unsigned short* __restrict__ WtH, const unsigned short* __restrict__ WtL,
    const float* __restrict__ bias,
    float* __restrict__ Cf, unsigned short* __restrict__ Hhi,
    unsigned short* __restrict__ Hlo, int N, int K) {
  __shared__ unsigned short AsH[2][4096], AsL[2][4096], BsH[2][4096], BsL[2][4096];
  const int t = threadIdx.x, l = t & 63, w = t >> 6;
  const int wm = w >> 1, wn = w & 1, lr = l & 15, lg = l >> 4;
  const int m0 = blockIdx.y * 32, n0 = blockIdx.x * 32;
  const int lr7 = lr & 7;

  auto stage = [&](int cur, int k0) {
#pragma unroll
    for (int r = 0; r < 2; ++r) {
      int g = r * 256 + t;
      int row = g >> 4, gc = g & 15;
      size_t co = (size_t)k0 + ((gc ^ (row & 7)) << 3);
      size_t ao = (size_t)(m0 + row) * K + co;
      size_t bo = (size_t)(n0 + row) * K + co;
      int db = (r * 256 + (t & 192)) * 16;
      gl_lds16(Ahi + ao, (char*)AsH[cur] + db);
      gl_lds16(Alo + ao, (char*)AsL[cur] + db);
      gl_lds16(WtH + bo, (char*)BsH[cur] + db);
      gl_lds16(WtL + bo, (char*)BsL[cur] + db);
    }
  };

  f32x4v acc = {0.f, 0.f, 0.f, 0.f};
  stage(0, 0);
  __syncthreads();
  int cur = 0;
  for (int k0 = 0; k0 < K; k0 += 128) {
    if (k0 + 128 < K) stage(cur ^ 1, k0 + 128);
#pragma unroll
    for (int ks = 0; ks < 4; ++ks) {
      int sl = ((ks * 4 + lg) ^ lr7) << 4;
      int ab = (wm * 16 + lr) * 256 + sl;
      int bb = (wn * 16 + lr) * 256 + sl;
      short8 ah = *(const short8*)((const char*)AsH[cur] + ab);
      short8 al = *(const short8*)((const char*)AsL[cur] + ab);
      short8 bh = *(const short8*)((const char*)BsH[cur] + bb);
      short8 bl = *(const short8*)((const char*)BsL[cur] + bb);
      acc = __builtin_amdgcn_mfma_f32_16x16x32_bf16(ah, bh, acc, 0, 0, 0);
      acc = __builtin_amdgcn_mfma_f32_16x16x32_bf16(ah, bl, acc, 0, 0, 0);
      acc = __builtin_amdgcn_mfma_f32_16x16x32_bf16(al, bh, acc, 0, 0, 0);
    }
    __syncthreads();
    cur ^= 1;
  }

  int n = n0 + wn * 16 + lr;
  float be = bias[n];
#pragma unroll
  for (int r = 0; r < 4; ++r) {
    int m = m0 + wm * 16 + lg * 4 + r;
    float v = acc[r] + be;
    if (RELU) {
      v = fmaxf(v, 0.f);
      unsigned short h = f2bf(v);
      Hhi[m * N + n] = h;
      Hlo[m * N + n] = f2bf(v - bf2f(h));
    } else {
      Cf[m * N + n] = v;
    }
  }
}

// ---------------------------------------------------------------------------
// Fused Jacobian-trace kernel v4. 2 samples per block, grid (4 cb, 256 pairs).
// 4 waves 2x2, wave tile 64x64 (4x4 16x16x32 frags), BK=32, K=512.
//   G[b][j] = sum_c w2n[b][c]*(D2[c]*w3t[j][c])   (phase 1, packed to bf16)
//   J[b][j] = sum_a w1t[b][a]*(D0[a]*w0y[j][a])   (phase 2)
//   klp[cb][s] = sum_{b in chunk, j} D1[b]*J[b][j]*G[b][j]
// LDS [ks][row][16B] layout: b128 fragment reads conflict-free, no swizzle.
// Weights staged once per k0, masked per-sample in-register -> 51 FLOP/B.
// ---------------------------------------------------------------------------
__global__ __launch_bounds__(256, 2) void jac_fused(
    const unsigned short* __restrict__ w1t, const unsigned short* __restrict__ w0y,
    const unsigned short* __restrict__ w2n, const unsigned short* __restrict__ w3t,
    const unsigned short* __restrict__ d0m, const unsigned short* __restrict__ d1m,
    const unsigned short* __restrict__ d2m, float* __restrict__ klp) {
  __shared__ unsigned short As[2][4][128][8];   // 8 KB x2
  __shared__ unsigned short Bs[2][4][128][8];   // 8 KB x2
  __shared__ unsigned short Ms[3][2][512];      // 6 KB
  __shared__ float red[8];
  const int cb = blockIdx.x, s0 = blockIdx.y * 2;
  const int t = threadIdx.x, l = t & 63, w = t >> 6;
  const int wm = w >> 1, wn = w & 1, lr = l & 15, lg = l >> 4;

  if (w < 3) {
    const unsigned short* src = (w == 0) ? d0m : (w == 1) ? d1m : d2m;
    gl_lds16(src + (size_t)s0 * 512 + l * 8, (void*)&Ms[w][0][0]);
    gl_lds16(src + (size_t)(s0 + 1) * 512 + l * 8, (void*)&Ms[w][1][0]);
  }
  __syncthreads();
  {
    unsigned* M = (unsigned*)&Ms[0][0][0];
#pragma unroll
    for (int q = 0; q < 6; ++q) {
      unsigned v = M[q * 256 + t];
      M[q * 256 + t] = ((v & 0xFFFFu) ? 0xFFFFu : 0u) | ((v >> 16) ? 0xFFFF0000u : 0u);
    }
  }

  auto stage = [&](int buf, const unsigned short* Ab, const unsigned short* Bb,
                   int k0) {
#pragma unroll
    for (int i = 0; i < 2; ++i) {
      int u = i * 4 + w;
      int ks = u & 3, sp = u >> 2;
      gl_lds16(Ab + (size_t)(cb * 128 + sp * 64 + l) * 512 + k0 + ks * 8,
               (void*)&As[buf][ks][sp * 64][0]);
      gl_lds16(Bb + (size_t)(sp * 64 + l) * 512 + k0 + ks * 8,
               (void*)&Bs[buf][ks][sp * 64][0]);
    }
  };

  f32x4v a0[4][4], a1[4][4];
  auto phase = [&](const unsigned short* Ab, const unsigned short* Bb, int mi) {
#pragma unroll
    for (int mt = 0; mt < 4; ++mt)
#pragma unroll
      for (int nt = 0; nt < 4; ++nt) {
        a0[mt][nt] = f32x4v{0.f, 0.f, 0.f, 0.f};
        a1[mt][nt] = f32x4v{0.f, 0.f, 0.f, 0.f};
      }
    stage(0, Ab, Bb, 0);
    __syncthreads();
    int cur = 0;
    for (int k0 = 0; k0 < 512; k0 += 32) {
      if (k0 + 32 < 512) stage(cur ^ 1, Ab, Bb, k0 + 32);
      u16x8 mk0 = *(const u16x8*)&Ms[mi][0][k0 + lg * 8];
      u16x8 mk1 = *(const u16x8*)&Ms[mi][1][k0 + lg * 8];
      short8 af[4];
#pragma unroll
      for (int mt = 0; mt < 4; ++mt)
        af[mt] = *(const short8*)&As[cur][lg][wm * 64 + mt * 16 + lr][0];
#pragma unroll
      for (int nt = 0; nt < 4; ++nt) {
        u16x8 bv = *(const u16x8*)&Bs[cur][lg][wn * 64 + nt * 16 + lr][0];
        short8 b0 = (short8)(bv & mk0);
        short8 b1 = (short8)(bv & mk1);
#pragma unroll
        for (int mt = 0; mt < 4; ++mt) {
          a0[mt][nt] = __builtin_amdgcn_mfma_f32_16x16x32_bf16(af[mt], b0,
                                                               a0[mt][nt], 0, 0, 0);
          a1[mt][nt] = __builtin_amdgcn_mfma_f32_16x16x32_bf16(af[mt], b1,
                                                               a1[mt][nt], 0, 0, 0);
        }
      }
      __syncthreads();
      cur ^= 1;
    }
  };

  // Phase G (mask D2), pack accumulators to bf16 pairs (64 VGPR total).
  phase(w2n, w3t, 2);
  unsigned pg0[4][4][2], pg1[4][4][2];
#pragma unroll
  for (int mt = 0; mt < 4; ++mt)
#pragma unroll
    for (int nt = 0; nt < 4; ++nt) {
      asm("v_cvt_pk_bf16_f32 %0, %1, %2" : "=v"(pg0[mt][nt][0])
          : "v"(a0[mt][nt][0]), "v"(a0[mt][nt][1]));
      asm("v_cvt_pk_bf16_f32 %0, %1, %2" : "=v"(pg0[mt][nt][1])
          : "v"(a0[mt][nt][2]), "v"(a0[mt][nt][3]));
      asm("v_cvt_pk_bf16_f32 %0, %1, %2" : "=v"(pg1[mt][nt][0])
          : "v"(a1[mt][nt][0]), "v"(a1[mt][nt][1]));
      asm("v_cvt_pk_bf16_f32 %0, %1, %2" : "=v"(pg1[mt][nt][1])
          : "v"(a1[mt][nt][2]), "v"(a1[mt][nt][3]));
    }

  // Phase J (mask D0) into the same accumulators.
  phase(w1t, w0y, 0);

  // Dot: part[s] = sum D1[b] * J * G
  float p0 = 0.f, p1 = 0.f;
#pragma unroll
  for (int mt = 0; mt < 4; ++mt) {
    int bl = cb * 128 + wm * 64 + mt * 16 + lg * 4;
    ushort4 m40 = *(const ushort4*)&Ms[1][0][bl];
    ushort4 m41 = *(const ushort4*)&Ms[1][1][bl];
    unsigned short mm0[4] = {m40.x, m40.y, m40.z, m40.w};
    unsigned short mm1[4] = {m41.x, m41.y, m41.z, m41.w};
#pragma unroll
    for (int r = 0; r < 4; ++r) {
#pragma unroll
      for (int nt = 0; nt < 4; ++nt) {
        unsigned pw0 = pg0[mt][nt][r >> 1];
        unsigned pw1 = pg1[mt][nt][r >> 1];
        unsigned short g0 = (r & 1) ? (unsigned short)(pw0 >> 16)
                                    : (unsigned short)(pw0 & 0xFFFFu);
        unsigned short g1 = (r & 1) ? (unsigned short)(pw1 >> 16)
                                    : (unsigned short)(pw1 & 0xFFFFu);
        if (mm0[r]) p0 = fmaf(a0[mt][nt][r], bf2f(g0), p0);
        if (mm1[r]) p1 = fmaf(a1[mt][nt][r], bf2f(g1), p1);
      }
    }
  }
#pragma unroll
  for (int off = 1; off < 64; off <<= 1) {
    p0 += __shfl_xor(p0, off);
    p1 += __shfl_xor(p1, off);
  }
  if (l == 0) { red[w * 2] = p0; red[w * 2 + 1] = p1; }
  __syncthreads();
  if (t < 2) {
    klp[cb * 512 + s0 + t] = red[t] + red[2 + t] + red[4 + t] + red[6 + t];
  }
}

// y += sum_i db[i]*ky[i];  lp += sum_i db[i]*(sum_{4 chunks} klp[i][cb][s])
__global__ __launch_bounds__(256) void step_update(float* __restrict__ y,
                                                   float* __restrict__ lp,
                                                   const float* __restrict__ ky,
                                                   const float* __restrict__ klp_part,
                                                   Coef6 db) {
  int i = blockIdx.x * 256 + threadIdx.x;
  if (i < 65536) {
    float a = y[i];
#pragma unroll
    for (int j = 0; j < 6; ++j) a += db.v[j] * ky[j * 65536 + i];
    y[i] = a;
  }
  if (i < 512) {
    float l = lp[i];
#pragma unroll
    for (int j = 0; j < 6; ++j) {
      const float* kp = klp_part + j * 2048;
      float tr = kp[i] + kp[512 + i] + kp[1024 + i] + kp[1536 + i];
      l += db.v[j] * tr;
    }
    lp[i] = l;
  }
}

__global__ __launch_bounds__(64) void finalize(const float* __restrict__ y,
                                               const float* __restrict__ lp,
                                               float* __restrict__ out) {
  int s = blockIdx.x, l = threadIdx.x;
  float v0 = y[s * 128 + l], v1 = y[s * 128 + 64 + l];
  float sum = v0 * v0 + v1 * v1;
#pragma unroll
  for (int off = 32; off; off >>= 1) sum += __shfl_down(sum, off);
  if (l == 0) out[s] = lp[s] + (-0.5f) * (1.8378770664093453f + sum);
}

// ---------------------------------------------------------------------------
extern "C" void kernel_launch(void* const* d_in, const int* in_sizes, int n_in,
                              void* d_out, int out_size, void* d_ws, size_t ws_size,
                              hipStream_t stream) {
  const float* y_in = (const float*)d_in[0];
  const float* Ws0 = (const float*)d_in[1];
  const float* bs0 = (const float*)d_in[2];
  const float* Ws1 = (const float*)d_in[3];
  const float* bs1 = (const float*)d_in[4];
  const float* Ws2 = (const float*)d_in[5];
  const float* bs2 = (const float*)d_in[6];
  const float* Ws3 = (const float*)d_in[7];
  const float* bs3 = (const float*)d_in[8];
  float* out = (float*)d_out;

  char* ws = (char*)d_ws;
  size_t off = 0;
  auto alloc = [&](size_t bytes) {
    void* p = ws + off;
    off = (off + bytes + 255) & ~(size_t)255;
    return p;
  };
  float* y  = (float*)alloc(65536 * 4);
  float* lp = (float*)alloc(512 * 4);
  unsigned short* h0hi = (unsigned short*)alloc(262144 * 2);
  unsigned short* h0lo = (unsigned short*)alloc(262144 * 2);
  unsigned short* h1hi = (unsigned short*)alloc(262144 * 2);
  unsigned short* h1lo = (unsigned short*)alloc(262144 * 2);
  unsigned short* h2hi = (unsigned short*)alloc(262144 * 2);
  unsigned short* h2lo = (unsigned short*)alloc(262144 * 2);
  float* ky  = (float*)alloc(6 * 65536 * 4);
  float* klp = (float*)alloc(6 * 2048 * 4);
  unsigned short* w0y  = (unsigned short*)alloc(65536 * 2);
  unsigned short* w0tH = (unsigned short*)alloc(65536 * 2);
  unsigned short* w0tL = (unsigned short*)alloc(65536 * 2);
  unsigned short* w1tH = (unsigned short*)alloc(262144 * 2);
  unsigned short* w1tL = (unsigned short*)alloc(262144 * 2);
  unsigned short* w2tH = (unsigned short*)alloc(262144 * 2);
  unsigned short* w2tL = (unsigned short*)alloc(262144 * 2);
  unsigned short* w3tH = (unsigned short*)alloc(65536 * 2);
  unsigned short* w3tL = (unsigned short*)alloc(65536 * 2);
  unsigned short* w2n  = (unsigned short*)alloc(262144 * 2);
  (void)ws_size; (void)in_sizes; (void)n_in; (void)out_size;

  static const double DT = -0.1;
  static const double TC[6] = {0.0, 0.161, 0.327, 0.9, 0.9800255409045097, 1.0};
  static const double TA[6][5] = {
      {0, 0, 0, 0, 0},
      {0.161, 0, 0, 0, 0},
      {-0.008480655492356989, 0.335480655492357, 0, 0, 0},
      {2.8971530571054935, -6.359448489975075, 4.3622954328695815, 0, 0},
      {5.325864828439257, -11.748883564062828, 7.4955393428898365, -0.09249506636175525, 0},
      {5.86145544294642, -12.92096931784711, 8.159367898576159, -0.071584973281401,
       -0.028269050394068383}};
  static const double TB[6] = {0.09646076681806523, 0.01, 0.4798896504144996,
                               1.379008574103742, -3.290069515436081, 2.324710524099774};

  init_state<<<dim3(256), dim3(256), 0, stream>>>(y_in, y, lp);

  for (int blk = 0; blk < 2; ++blk) {
    const float* W0 = Ws0 + blk * 129 * 512;
    const float* b0 = bs0 + blk * 512;
    const float* W1 = Ws1 + blk * 262144;
    const float* b1 = bs1 + blk * 512;
    const float* W2 = Ws2 + blk * 262144;
    const float* b2 = bs2 + blk * 512;
    const float* W3 = Ws3 + blk * 65536;
    const float* b3 = bs3 + blk * 128;

    cast_weights<<<dim3(3840), dim3(256), 0, stream>>>(
        W0, W1, W2, W3, w0y, w0tH, w0tL, w1tH, w1tL, w2tH, w2tL, w3tH, w3tL, w2n);

    for (int n = 0; n < 10; ++n) {
      float t = 1.0f + (-0.1f) * (float)n;
      for (int i = 0; i < 6; ++i) {
        float ti = t + (float)(TC[i] * DT);
        Coef5 ca;
        for (int j = 0; j < 5; ++j) ca.v[j] = (j < i) ? (float)(DT * TA[i][j]) : 0.f;

        fwd_l0<<<dim3(16, 16), 256, 0, stream>>>(
            y, ky, ca, i, w0tH, w0tL, b0, W0, ti, h0hi, h0lo);
        fwd_mfma<true><<<dim3(16, 16), 256, 0, stream>>>(
            h0hi, h0lo, w1tH, w1tL, b1, nullptr, h1hi, h1lo, 512, 512);
        fwd_mfma<true><<<dim3(16, 16), 256, 0, stream>>>(
            h1hi, h1lo, w2tH, w2tL, b2, nullptr, h2hi, h2lo, 512, 512);
        fwd_mfma<false><<<dim3(4, 16), 256, 0, stream>>>(
            h2hi, h2lo, w3tH, w3tL, b3, ky + i * 65536, nullptr, nullptr, 128, 512);
        jac_fused<<<dim3(4, 256), 256, 0, stream>>>(
            w1tH, w0y, w2n, w3tH, h0hi, h1hi, h2hi, klp + i * 2048);
      }
      Coef6 db;
      for (int i2 = 0; i2 < 6; ++i2) db.v[i2] = (float)(DT * TB[i2]);
      step_update<<<dim3(256), dim3(256), 0, stream>>>(y, lp, ky, klp, db);
    }
  }
  finalize<<<dim3(512), dim3(64), 0, stream>>>(y, lp, out);
}